// Round 9
// baseline (157.384 us; speedup 1.0000x reference)
//
#include <hip/hip_runtime.h>

// Problem constants (from reference): B=64, H=W=512, 256 zones.
#define NZ    256
#define NB    64
#define NPIX  (512 * 512)

// Pass-1 geometry: 32 elems/thread -> 2048 blocks.
#define EPT1  32
#define CHUNK1 (256 * EPT1)        // 8192 px per block
#define BPB1  (NPIX / CHUNK1)      // 32 blocks per batch
#define NBLK1 (NB * BPB1)          // 2048

// Pass-2 geometry: 16 elems/thread -> 4096 blocks (near stream floor).
#define CHUNK3 (256 * 16)
#define BPB3  (NPIX / CHUNK3)      // 64
#define NBLK3 (NB * BPB3)          // 4096

// Monotonic float->unsigned encoding: preserves total order.
// enc()>0 for every real float (0 only for bits 0xFFFFFFFF, a NaN) -> 0 is a
// safe "empty" sentinel; dec(0)=NaN matches no pixel (empty zone semantics).
__device__ __forceinline__ unsigned enc(float f) {
    unsigned b = __float_as_uint(f);
    return b ^ ((b & 0x80000000u) ? 0xFFFFFFFFu : 0x80000000u);
}
__device__ __forceinline__ float dec(unsigned u) {
    unsigned b = (u & 0x80000000u) ? (u ^ 0x80000000u) : ~u;
    return __uint_as_float(b);
}

// Pass 1: segmented max WITHOUT any LDS atomic in the hot loop.
// R2-R8 finding: scattered ds_max_u32 costs ~70-100 cy per wave-INSTRUCTION
// flat (invariant to lanes/layout/privacy/memory-level); 1024 such instrs/CU
// == the entire 45us wall. Here the LDS table is only a RACY HINT maintained
// with plain ds_write (cheap, ~10cy class like mask_kernel's reads, hidden
// under load latency); ground truth is a predicated GLOBAL atomicMax into
// gtab[batch][zone] (fire-and-forget, ~2M lanes total spread over 16K words).
// Correctness: hint[z] only ever holds values that were ALSO pushed to gtab
// under the same predicate, so any pixel filtered out (e <= hint[z]) is
// dominated by a value already in gtab; the true zone max always lands.
__global__ __launch_bounds__(256) void segmax_part(
        const float* __restrict__ inp, const int* __restrict__ zones,
        unsigned* __restrict__ gtab) {
    __shared__ unsigned hint[NZ];
    const int t = threadIdx.x;
    hint[t] = 0u;  // blockDim == NZ == 256
    __syncthreads();

    const int batch = blockIdx.x / BPB1;
    const int chunk = blockIdx.x % BPB1;
    const long base = (long)batch * NPIX + (long)chunk * CHUNK1;
    const float4* in4 = (const float4*)(inp + base);
    const int4*   z4  = (const int4*)(zones + base);
    unsigned* __restrict__ grow = gtab + batch * NZ;

#pragma unroll
    for (int h = 0; h < EPT1 / 4; ++h) {
        float4 v = in4[h * 256 + t];
        int4   z = z4[h * 256 + t];
        unsigned e0 = enc(v.x), e1 = enc(v.y), e2 = enc(v.z), e3 = enc(v.w);
        unsigned c0 = hint[z.x], c1 = hint[z.y], c2 = hint[z.z], c3 = hint[z.w];
        if (e0 > c0) { hint[z.x] = e0; atomicMax(&grow[z.x], e0); }
        if (e1 > c1) { hint[z.y] = e1; atomicMax(&grow[z.y], e1); }
        if (e2 > c2) { hint[z.z] = e2; atomicMax(&grow[z.z], e2); }
        if (e3 > c3) { hint[z.w] = e3; atomicMax(&grow[z.w], e3); }
    }
}

// Pass 2: mask = (x == segmax[zone]) as int32 0/1; per-block partial count to
// a private slot (contended global atomicAdd was the 192us R1 bug). Reads
// gtab directly (kernel boundary makes pass-1 atomics visible) and decodes.
__global__ __launch_bounds__(256) void mask_kernel(
        const float* __restrict__ inp, const int* __restrict__ zones,
        const unsigned* __restrict__ gtab,
        int* __restrict__ mask, int* __restrict__ partial) {
    __shared__ float smax[NZ];
    __shared__ int wsum[4];
    const int t = threadIdx.x;

    const int batch = blockIdx.x / BPB3;
    const int chunk = blockIdx.x % BPB3;

    smax[t] = dec(gtab[batch * NZ + t]);  // empty zone -> NaN, matches nothing
    __syncthreads();

    const long base = (long)batch * NPIX + (long)chunk * CHUNK3;
    const float4* in4 = (const float4*)(inp + base);
    const int4*   z4  = (const int4*)(zones + base);
    int4* m4 = (int4*)(mask + base);

    int c = 0;
#pragma unroll
    for (int it = 0; it < 4; ++it) {
        float4 v = in4[it * 256 + t];
        int4   z = z4[it * 256 + t];
        int4 m;
        m.x = (v.x == smax[z.x]) ? 1 : 0;
        m.y = (v.y == smax[z.y]) ? 1 : 0;
        m.z = (v.z == smax[z.z]) ? 1 : 0;
        m.w = (v.w == smax[z.w]) ? 1 : 0;
        m4[it * 256 + t] = m;
        c += m.x + m.y + m.z + m.w;
    }

#pragma unroll
    for (int off = 32; off; off >>= 1) c += __shfl_down(c, off);
    if ((t & 63) == 0) wsum[t >> 6] = c;
    __syncthreads();
    if (t == 0) partial[blockIdx.x] = wsum[0] + wsum[1] + wsum[2] + wsum[3];
}

// Pass 3: single block sums the 4096 partials into the output counter.
__global__ __launch_bounds__(256) void count_kernel(
        const int* __restrict__ partial, int n, int* __restrict__ count) {
    __shared__ int wsum[4];
    const int t = threadIdx.x;
    int c = 0;
    for (int i = t; i < n; i += 256) c += partial[i];
#pragma unroll
    for (int off = 32; off; off >>= 1) c += __shfl_down(c, off);
    if ((t & 63) == 0) wsum[t >> 6] = c;
    __syncthreads();
    if (t == 0) *count = wsum[0] + wsum[1] + wsum[2] + wsum[3];
}

extern "C" void kernel_launch(void* const* d_in, const int* in_sizes, int n_in,
                              void* d_out, int out_size, void* d_ws, size_t ws_size,
                              hipStream_t stream) {
    const float* inp   = (const float*)d_in[0];
    const int*   zones = (const int*)d_in[1];
    int*         out   = (int*)d_out;   // [B*NPIX] mask + [1] n_centers, int32

    // Workspace layout:
    //   gtab   : NB*NZ u32 = 64 KB (zeroed each call -> deterministic replay)
    //   partial: NBLK3 i32 = 16 KB (fully overwritten each call)
    unsigned* gtab    = (unsigned*)d_ws;
    int*      partial = (int*)((char*)d_ws + (size_t)NB * NZ * 4);

    const long nmask = (long)NB * NPIX;  // == out_size - 1

    hipMemsetAsync(gtab, 0, (size_t)NB * NZ * 4, stream);
    segmax_part <<<NBLK1, 256, 0, stream>>>(inp, zones, gtab);
    mask_kernel <<<NBLK3, 256, 0, stream>>>(inp, zones, gtab, out, partial);
    count_kernel<<<1,     256, 0, stream>>>(partial, NBLK3, out + nmask);
}

// Round 10
// 76.700 us; speedup vs baseline: 2.0519x; 2.0519x over previous
//
#include <hip/hip_runtime.h>

// Problem constants (from reference): B=64, H=W=512, 256 zones.
#define NZ    256
#define NB    64
#define NPIX  (512 * 512)

// Pass-1 geometry: 32 elems/thread -> 2048 blocks.
#define EPT1  32
#define CHUNK1 (256 * EPT1)        // 8192 px per block
#define BPB1  (NPIX / CHUNK1)      // 32 blocks per batch
#define NBLK1 (NB * BPB1)          // 2048

// Wave-private tables (+8 stagger): plain writes race-safe within a wave.
#define NZP   264

// Pass-3 geometry: 16 elems/thread -> 4096 blocks (near stream floor).
#define CHUNK3 (256 * 16)
#define BPB3  (NPIX / CHUNK3)      // 64
#define NBLK3 (NB * BPB3)          // 4096

__device__ __forceinline__ unsigned umax2(unsigned a, unsigned b) { return a > b ? a : b; }

// Monotonic float->unsigned encoding: preserves total order.
// enc()==0 only for bits 0xFFFFFFFF (a NaN) -> safe "empty" sentinel; dec(0)=NaN.
__device__ __forceinline__ unsigned enc(float f) {
    unsigned b = __float_as_uint(f);
    return b ^ ((b & 0x80000000u) ? 0xFFFFFFFFu : 0x80000000u);
}
__device__ __forceinline__ float dec(unsigned u) {
    unsigned b = (u & 0x80000000u) ? (u ^ 0x80000000u) : ~u;
    return __uint_as_float(b);
}

// ABLATION PROBE: identical geometry and loads to segmax_part, ZERO LDS ops.
// Measures the pure load+VALU floor of the segmax loop structure. Its result
// goes to scratch (later overwritten by segmax_part's 'part' region).
__global__ __launch_bounds__(256) void probe_loads(
        const float* __restrict__ inp, const int* __restrict__ zones,
        unsigned* __restrict__ sink) {
    const int t = threadIdx.x;
    const int batch = blockIdx.x / BPB1;
    const int chunk = blockIdx.x % BPB1;
    const long base = (long)batch * NPIX + (long)chunk * CHUNK1;
    const float4* in4 = (const float4*)(inp + base);
    const int4*   z4  = (const int4*)(zones + base);
    unsigned acc = 0;
#pragma unroll
    for (int h = 0; h < EPT1 / 4; ++h) {
        float4 v = in4[h * 256 + t];
        int4   z = z4[h * 256 + t];
        acc += enc(v.x) + enc(v.y) + enc(v.z) + enc(v.w);
        acc += (unsigned)(z.x + z.y + z.z + z.w);
    }
    sink[(long)blockIdx.x * 256 + t] = acc;  // keeps all loads live
}

// Pass 1: segmax with NO ATOMICS. Wave-private table + in-wave retry:
//   c = tab[z]; while(any lane e > c){ losers rewrite; re-read }
// Within one wave, each round's colliding-write winner wrote a value > the c
// every lane just read -> table monotone increasing -> loop terminates with
// tab[z] = max of all contenders (deterministic). Cross-wave races impossible
// (tables are wave-private; merged after __syncthreads).
// R2-R8 finding being exploited: scattered ds_read/ds_write ~8cy/instr vs
// ds_atomic ~90cy/instr flat.
__global__ __launch_bounds__(256) void segmax_part(
        const float* __restrict__ inp, const int* __restrict__ zones,
        unsigned* __restrict__ part) {
    __shared__ unsigned sm[4 * NZP];
    const int t = threadIdx.x;
    const int wave = t >> 6;
    for (int i = t; i < 4 * NZP; i += 256) sm[i] = 0u;
    __syncthreads();

    unsigned* mytab = &sm[wave * NZP];

    const int batch = blockIdx.x / BPB1;
    const int chunk = blockIdx.x % BPB1;
    const long base = (long)batch * NPIX + (long)chunk * CHUNK1;
    const float4* in4 = (const float4*)(inp + base);
    const int4*   z4  = (const int4*)(zones + base);

#pragma unroll
    for (int h = 0; h < EPT1 / 4; ++h) {
        float4 v = in4[h * 256 + t];
        int4   z = z4[h * 256 + t];
        unsigned e0 = enc(v.x), e1 = enc(v.y), e2 = enc(v.z), e3 = enc(v.w);

        unsigned c;
        c = mytab[z.x];
        while (__any(e0 > c)) { if (e0 > c) mytab[z.x] = e0; c = mytab[z.x]; }
        c = mytab[z.y];
        while (__any(e1 > c)) { if (e1 > c) mytab[z.y] = e1; c = mytab[z.y]; }
        c = mytab[z.z];
        while (__any(e2 > c)) { if (e2 > c) mytab[z.z] = e2; c = mytab[z.z]; }
        c = mytab[z.w];
        while (__any(e3 > c)) { if (e3 > c) mytab[z.w] = e3; c = mytab[z.w]; }
    }
    __syncthreads();

    // Merge 4 wave-copies (lanes read consecutive words -> conflict-free).
    unsigned m = umax2(umax2(sm[t], sm[NZP + t]),
                       umax2(sm[2 * NZP + t], sm[3 * NZP + t]));
    part[(long)blockIdx.x * NZ + t] = m;  // coalesced 1 KB store
}

// Pass 2: one block per batch; thread t max-combines zone t over the batch's
// 32 chunk tables and stores the DECODED float (empty zone -> NaN).
__global__ __launch_bounds__(256) void segmax_reduce(
        const unsigned* __restrict__ part, float* __restrict__ segf) {
    const int t = threadIdx.x;
    const int batch = blockIdx.x;
    const unsigned* p = part + (long)batch * BPB1 * NZ;
    unsigned m = 0u;
#pragma unroll 8
    for (int c = 0; c < BPB1; ++c) m = umax2(m, p[c * NZ + t]);
    segf[batch * NZ + t] = dec(m);
}

// Pass 3: mask = (x == segmax[zone]) as int32 0/1; per-block partial count to
// a private slot (contended global atomicAdd was the 192us R1 bug).
__global__ __launch_bounds__(256) void mask_kernel(
        const float* __restrict__ inp, const int* __restrict__ zones,
        const float* __restrict__ segf,
        int* __restrict__ mask, int* __restrict__ partial) {
    __shared__ float smax[NZ];
    __shared__ int wsum[4];
    const int t = threadIdx.x;

    const int batch = blockIdx.x / BPB3;
    const int chunk = blockIdx.x % BPB3;

    smax[t] = segf[batch * NZ + t];
    __syncthreads();

    const long base = (long)batch * NPIX + (long)chunk * CHUNK3;
    const float4* in4 = (const float4*)(inp + base);
    const int4*   z4  = (const int4*)(zones + base);
    int4* m4 = (int4*)(mask + base);

    int c = 0;
#pragma unroll
    for (int it = 0; it < 4; ++it) {
        float4 v = in4[it * 256 + t];
        int4   z = z4[it * 256 + t];
        int4 m;
        m.x = (v.x == smax[z.x]) ? 1 : 0;
        m.y = (v.y == smax[z.y]) ? 1 : 0;
        m.z = (v.z == smax[z.z]) ? 1 : 0;
        m.w = (v.w == smax[z.w]) ? 1 : 0;
        m4[it * 256 + t] = m;
        c += m.x + m.y + m.z + m.w;
    }

#pragma unroll
    for (int off = 32; off; off >>= 1) c += __shfl_down(c, off);
    if ((t & 63) == 0) wsum[t >> 6] = c;
    __syncthreads();
    if (t == 0) partial[blockIdx.x] = wsum[0] + wsum[1] + wsum[2] + wsum[3];
}

// Pass 4: single block sums the 4096 partials into the output counter.
__global__ __launch_bounds__(256) void count_kernel(
        const int* __restrict__ partial, int n, int* __restrict__ count) {
    __shared__ int wsum[4];
    const int t = threadIdx.x;
    int c = 0;
    for (int i = t; i < n; i += 256) c += partial[i];
#pragma unroll
    for (int off = 32; off; off >>= 1) c += __shfl_down(c, off);
    if ((t & 63) == 0) wsum[t >> 6] = c;
    __syncthreads();
    if (t == 0) *count = wsum[0] + wsum[1] + wsum[2] + wsum[3];
}

extern "C" void kernel_launch(void* const* d_in, const int* in_sizes, int n_in,
                              void* d_out, int out_size, void* d_ws, size_t ws_size,
                              hipStream_t stream) {
    const float* inp   = (const float*)d_in[0];
    const int*   zones = (const int*)d_in[1];
    int*         out   = (int*)d_out;   // [B*NPIX] mask + [1] n_centers, int32

    // Workspace layout (~2.1 MB, every region fully overwritten each call):
    //   part (2 MB) — ALSO used as the probe's sink (probe runs first, then
    //                 segmax_part fully overwrites it; final output unaffected)
    //   segf   : NB*NZ f32 = 64 KB
    //   partial: NBLK3 i32 = 16 KB
    unsigned* part    = (unsigned*)d_ws;
    float*    segf    = (float*)((char*)d_ws + (size_t)NBLK1 * NZ * 4);
    int*      partial = (int*)((char*)d_ws + (size_t)NBLK1 * NZ * 4 + (size_t)NB * NZ * 4);

    const long nmask = (long)NB * NPIX;  // == out_size - 1

    probe_loads  <<<NBLK1, 256, 0, stream>>>(inp, zones, part);  // ablation probe
    segmax_part  <<<NBLK1, 256, 0, stream>>>(inp, zones, part);
    segmax_reduce<<<NB,    256, 0, stream>>>(part, segf);
    mask_kernel  <<<NBLK3, 256, 0, stream>>>(inp, zones, segf, out, partial);
    count_kernel <<<1,     256, 0, stream>>>(partial, NBLK3, out + nmask);
}

// Round 11
// 57.588 us; speedup vs baseline: 2.7329x; 1.3319x over previous
//
#include <hip/hip_runtime.h>

// Problem constants (from reference): B=64, H=W=512, 256 zones.
#define NZ    256
#define NB    64
#define NPIX  (512 * 512)

// Pass-1 geometry: 32 elems/thread -> 2048 blocks (measured ~21us in R10).
#define EPT1  32
#define CHUNK1 (256 * EPT1)        // 8192 px per block
#define BPB1  (NPIX / CHUNK1)      // 32 blocks per batch
#define NBLK1 (NB * BPB1)          // 2048

// Wave-private tables (+8 stagger de-aliases banks across copies).
#define NZP   264

// Pass-3 geometry: 16 elems/thread -> 4096 blocks (~9-13us, near stream floor).
#define CHUNK3 (256 * 16)
#define BPB3  (NPIX / CHUNK3)      // 64
#define NBLK3 (NB * BPB3)          // 4096

__device__ __forceinline__ unsigned umax2(unsigned a, unsigned b) { return a > b ? a : b; }

// Monotonic float->unsigned encoding: preserves total order.
// enc()==0 only for bits 0xFFFFFFFF (a NaN) -> safe "empty" sentinel; dec(0)=NaN.
__device__ __forceinline__ unsigned enc(float f) {
    unsigned b = __float_as_uint(f);
    return b ^ ((b & 0x80000000u) ? 0xFFFFFFFFu : 0x80000000u);
}
__device__ __forceinline__ float dec(unsigned u) {
    unsigned b = (u & 0x80000000u) ? (u ^ 0x80000000u) : ~u;
    return __uint_as_float(b);
}

// Pass 1: segmax with NO ATOMICS — wave-private VOLATILE table + in-wave retry.
// R10 evidence: this structure ran ~21us vs ~45us for every ds_atomic variant
// AND ~45us for batched loads alone (probe) — interleaved load->cheap-DS wins.
// volatile fixes R10's absmax=1.0: forces real ds_read/ds_write each access so
// a lane's re-read always sees the winning lane's write (compiler was
// forwarding/caching the unsynchronized cross-lane LDS traffic).
// Algorithm: c = tab[z]; while any lane's e beats its c: losers-with-bigger-e
// rewrite, all re-read. Table is monotone increasing (every write exceeds the
// value just read), so the fixed point is tab[z] = max of contenders. Lanes
// with distinct z touch distinct addresses (wave-private table -> no
// cross-wave interference; merged after __syncthreads).
__global__ __launch_bounds__(256) void segmax_part(
        const float* __restrict__ inp, const int* __restrict__ zones,
        unsigned* __restrict__ part) {
    __shared__ unsigned sm[4 * NZP];
    const int t = threadIdx.x;
    const int wave = t >> 6;
    for (int i = t; i < 4 * NZP; i += 256) sm[i] = 0u;
    __syncthreads();

    volatile unsigned* mytab = &sm[wave * NZP];

    const int batch = blockIdx.x / BPB1;
    const int chunk = blockIdx.x % BPB1;
    const long base = (long)batch * NPIX + (long)chunk * CHUNK1;
    const float4* in4 = (const float4*)(inp + base);
    const int4*   z4  = (const int4*)(zones + base);

#pragma unroll
    for (int h = 0; h < EPT1 / 4; ++h) {
        float4 v = in4[h * 256 + t];
        int4   z = z4[h * 256 + t];
        unsigned e0 = enc(v.x), e1 = enc(v.y), e2 = enc(v.z), e3 = enc(v.w);

        unsigned c;
        c = mytab[z.x];
        while (__any(e0 > c)) { if (e0 > c) mytab[z.x] = e0; c = mytab[z.x]; }
        c = mytab[z.y];
        while (__any(e1 > c)) { if (e1 > c) mytab[z.y] = e1; c = mytab[z.y]; }
        c = mytab[z.z];
        while (__any(e2 > c)) { if (e2 > c) mytab[z.z] = e2; c = mytab[z.z]; }
        c = mytab[z.w];
        while (__any(e3 > c)) { if (e3 > c) mytab[z.w] = e3; c = mytab[z.w]; }
    }
    __syncthreads();

    // Merge 4 wave-copies (lanes read consecutive words -> conflict-free).
    unsigned m = umax2(umax2(sm[t], sm[NZP + t]),
                       umax2(sm[2 * NZP + t], sm[3 * NZP + t]));
    part[(long)blockIdx.x * NZ + t] = m;  // coalesced 1 KB store
}

// Pass 2: one block per batch; thread t max-combines zone t over the batch's
// 32 chunk tables and stores the DECODED float (empty zone -> NaN).
__global__ __launch_bounds__(256) void segmax_reduce(
        const unsigned* __restrict__ part, float* __restrict__ segf) {
    const int t = threadIdx.x;
    const int batch = blockIdx.x;
    const unsigned* p = part + (long)batch * BPB1 * NZ;
    unsigned m = 0u;
#pragma unroll 8
    for (int c = 0; c < BPB1; ++c) m = umax2(m, p[c * NZ + t]);
    segf[batch * NZ + t] = dec(m);
}

// Pass 3: mask = (x == segmax[zone]) as int32 0/1; per-block partial count to
// a private slot (contended global atomicAdd was the 192us R1 bug).
__global__ __launch_bounds__(256) void mask_kernel(
        const float* __restrict__ inp, const int* __restrict__ zones,
        const float* __restrict__ segf,
        int* __restrict__ mask, int* __restrict__ partial) {
    __shared__ float smax[NZ];
    __shared__ int wsum[4];
    const int t = threadIdx.x;

    const int batch = blockIdx.x / BPB3;
    const int chunk = blockIdx.x % BPB3;

    smax[t] = segf[batch * NZ + t];
    __syncthreads();

    const long base = (long)batch * NPIX + (long)chunk * CHUNK3;
    const float4* in4 = (const float4*)(inp + base);
    const int4*   z4  = (const int4*)(zones + base);
    int4* m4 = (int4*)(mask + base);

    int c = 0;
#pragma unroll
    for (int it = 0; it < 4; ++it) {
        float4 v = in4[it * 256 + t];
        int4   z = z4[it * 256 + t];
        int4 m;
        m.x = (v.x == smax[z.x]) ? 1 : 0;
        m.y = (v.y == smax[z.y]) ? 1 : 0;
        m.z = (v.z == smax[z.z]) ? 1 : 0;
        m.w = (v.w == smax[z.w]) ? 1 : 0;
        m4[it * 256 + t] = m;
        c += m.x + m.y + m.z + m.w;
    }

#pragma unroll
    for (int off = 32; off; off >>= 1) c += __shfl_down(c, off);
    if ((t & 63) == 0) wsum[t >> 6] = c;
    __syncthreads();
    if (t == 0) partial[blockIdx.x] = wsum[0] + wsum[1] + wsum[2] + wsum[3];
}

// Pass 4: single block sums the 4096 partials into the output counter.
__global__ __launch_bounds__(256) void count_kernel(
        const int* __restrict__ partial, int n, int* __restrict__ count) {
    __shared__ int wsum[4];
    const int t = threadIdx.x;
    int c = 0;
    for (int i = t; i < n; i += 256) c += partial[i];
#pragma unroll
    for (int off = 32; off; off >>= 1) c += __shfl_down(c, off);
    if ((t & 63) == 0) wsum[t >> 6] = c;
    __syncthreads();
    if (t == 0) *count = wsum[0] + wsum[1] + wsum[2] + wsum[3];
}

extern "C" void kernel_launch(void* const* d_in, const int* in_sizes, int n_in,
                              void* d_out, int out_size, void* d_ws, size_t ws_size,
                              hipStream_t stream) {
    const float* inp   = (const float*)d_in[0];
    const int*   zones = (const int*)d_in[1];
    int*         out   = (int*)d_out;   // [B*NPIX] mask + [1] n_centers, int32

    // Workspace layout (~2.1 MB, every region fully overwritten each call ->
    // no memset needed, deterministic under graph replay):
    //   part   : NBLK1*NZ u32 = 2 MB
    //   segf   : NB*NZ   f32  = 64 KB
    //   partial: NBLK3   i32  = 16 KB
    unsigned* part    = (unsigned*)d_ws;
    float*    segf    = (float*)((char*)d_ws + (size_t)NBLK1 * NZ * 4);
    int*      partial = (int*)((char*)d_ws + (size_t)NBLK1 * NZ * 4 + (size_t)NB * NZ * 4);

    const long nmask = (long)NB * NPIX;  // == out_size - 1

    segmax_part  <<<NBLK1, 256, 0, stream>>>(inp, zones, part);
    segmax_reduce<<<NB,    256, 0, stream>>>(part, segf);
    mask_kernel  <<<NBLK3, 256, 0, stream>>>(inp, zones, segf, out, partial);
    count_kernel <<<1,     256, 0, stream>>>(partial, NBLK3, out + nmask);
}